// Round 6
// baseline (353.706 us; speedup 1.0000x reference)
//
#include <hip/hip_runtime.h>
#include <hip/hip_bf16.h>
#include <stdint.h>

#define CLASSES 100000
#define CHANNEL 128
#define BATCH   4096
#define NPAD    100096   // 782 * 128 (class dim padded to 128-tile multiple)
#define NBM     64       // row tiles (4096/64)
#define NBN     782      // class tiles of 128
#define NWG     (NBM * NBN)   // 50048 = 8 * 6256 -> exact XCD split
#define WGPX    (NWG / 8)     // 6256 workgroups per XCD chunk

typedef __bf16 bf16x8 __attribute__((ext_vector_type(8)));
typedef float  f32x4  __attribute__((ext_vector_type(4)));
typedef unsigned short u16x8 __attribute__((ext_vector_type(8)));

__device__ __forceinline__ unsigned short f32_to_bf16_rne(float f) {
    union { float f; uint32_t u; } v; v.f = f;
    uint32_t u = v.u;
    return (unsigned short)((u + 0x7fffu + ((u >> 16) & 1u)) >> 16);
}

// ---------------------------------------------------------------------------
// MFMA-fragment-tiled operand layout (both xn and wn):
//   element (frag16 f, k) stored at  [((f*4 + ks)*64 + lane)*8 + j]
//   so every GEMM fragment load is one lane-contiguous 1 KB read.
// ---------------------------------------------------------------------------

__global__ void xnorm_kernel(const float* __restrict__ x, unsigned short* __restrict__ xnt) {
    const int row  = blockIdx.x * 4 + (threadIdx.x >> 6);
    const int lane = threadIdx.x & 63;
    const float2 v = *reinterpret_cast<const float2*>(&x[(size_t)row * CHANNEL + lane * 2]);
    float s = v.x * v.x + v.y * v.y;
    #pragma unroll
    for (int off = 32; off >= 1; off >>= 1) s += __shfl_xor(s, off);
    const float inv = rsqrtf(fmaxf(s, 1e-12f));
    const int rf  = row >> 4;
    const int l15 = row & 15;
    const int k0  = lane * 2;
    const int ks  = k0 >> 5;
    const int lg  = (k0 >> 3) & 3;
    const int j   = k0 & 7;
    ushort2 o;
    o.x = f32_to_bf16_rne(v.x * inv);
    o.y = f32_to_bf16_rne(v.y * inv);
    *reinterpret_cast<ushort2*>(
        &xnt[((size_t)(rf * 4 + ks) * 64 + lg * 16 + l15) * 8 + j]) = o;
}

__global__ void wnorm_kernel(const float* __restrict__ w, unsigned short* __restrict__ wnt) {
    const int c = blockIdx.x * 256 + threadIdx.x;
    if (c >= NPAD) return;
    const int cf  = c >> 4;
    const int l15 = c & 15;
    if (c >= CLASSES) {
        u16x8 z;
        #pragma unroll
        for (int i = 0; i < 8; ++i) z[i] = 0;
        #pragma unroll
        for (int ks = 0; ks < 4; ++ks)
            #pragma unroll
            for (int lg = 0; lg < 4; ++lg)
                *reinterpret_cast<u16x8*>(
                    &wnt[((size_t)(cf * 4 + ks) * 64 + lg * 16 + l15) * 8]) = z;
        return;
    }
    float s = 0.f;
    #pragma unroll 8
    for (int ch = 0; ch < CHANNEL; ++ch) {
        const float v = w[(size_t)ch * CLASSES + c];
        s += v * v;
    }
    const float inv = rsqrtf(fmaxf(s, 1e-12f));
    #pragma unroll
    for (int ks = 0; ks < 4; ++ks) {
        #pragma unroll
        for (int lg = 0; lg < 4; ++lg) {
            u16x8 o;
            #pragma unroll
            for (int j = 0; j < 8; ++j) {
                const float v = w[(size_t)(ks * 32 + lg * 8 + j) * CLASSES + c];
                o[j] = f32_to_bf16_rne(v * inv);
            }
            *reinterpret_cast<u16x8*>(
                &wnt[((size_t)(cf * 4 + ks) * 64 + lg * 16 + l15) * 8]) = o;
        }
    }
}

// Block tile: 64 batch-rows x 128 classes; 4 waves (2x2), each 32 rows x 64 cols.
// R4: two-phase LDS epilogue (16.9 KB) -> 8 blocks/CU.
// R5: XCD-aware swizzle — each XCD gets a contiguous bn chunk (~98 panels
// = 3.1 MB wnt, fits its private 4 MB L2), bm fastest within the chunk.
// Cuts cross-XCD wnt re-fetch from HBM -> fewer read/write turnarounds
// stealing write bandwidth.
#define LDSW 132
__global__ __launch_bounds__(256) void cos_gemm_kernel(const unsigned short* __restrict__ xnt,
                                                       const unsigned short* __restrict__ wnt,
                                                       float* __restrict__ out) {
    // bijective XCD swizzle: NWG % 8 == 0
    const int bid  = blockIdx.x;
    const int wgid = (bid & 7) * WGPX + (bid >> 3);
    const int bm   = wgid & (NBM - 1);   // fastest within chunk -> panel reuse in this XCD's L2
    const int bn   = wgid >> 6;          // 0..781
    const int tid  = threadIdx.x;
    const int wv   = tid >> 6;
    const int wr   = wv >> 1;        // row half (0..1)
    const int wc   = wv & 1;         // col half (0..1)
    const int lane = tid & 63;
    const int l15  = lane & 15;
    const int lg   = lane >> 4;

    __shared__ float lds[32 * LDSW];

    f32x4 acc[2][4] = {};
    #pragma unroll
    for (int ks = 0; ks < 4; ++ks) {
        bf16x8 b[2], a[4];
        #pragma unroll
        for (int bf = 0; bf < 2; ++bf) {
            const int rf = bm * 4 + wr * 2 + bf;
            b[bf] = *reinterpret_cast<const bf16x8*>(
                &xnt[((size_t)(rf * 4 + ks) * 64 + lane) * 8]);
        }
        #pragma unroll
        for (int af = 0; af < 4; ++af) {
            const int cf = bn * 8 + wc * 4 + af;
            a[af] = *reinterpret_cast<const bf16x8*>(
                &wnt[((size_t)(cf * 4 + ks) * 64 + lane) * 8]);
        }
        #pragma unroll
        for (int bf = 0; bf < 2; ++bf)
            #pragma unroll
            for (int af = 0; af < 4; ++af)
                acc[bf][af] = __builtin_amdgcn_mfma_f32_16x16x32_bf16(a[af], b[bf], acc[bf][af], 0, 0, 0);
    }

    // Epilogue: phase ph stages rows [ph*32, ph*32+32) (held by waves wr==ph),
    // then all 4 waves stream them out, 2 rows x 512 B contiguous per store.
    const int  half = lane >> 5;          // 0..1
    const int  c4   = (lane & 31) * 4;    // 0..124
    const int  gcol = bn * 128 + c4;
    const bool colok = gcol < CLASSES;    // 100000 % 4 == 0: store fully in or out
    float* outbase = out + (size_t)(bm * 64) * CLASSES + gcol;

    #pragma unroll
    for (int ph = 0; ph < 2; ++ph) {
        if (ph) __syncthreads();          // drain phase-0 readers before overwrite
        if (wr == ph) {
            #pragma unroll
            for (int bf = 0; bf < 2; ++bf) {
                const int r = bf * 16 + l15;
                #pragma unroll
                for (int af = 0; af < 4; ++af)
                    *reinterpret_cast<f32x4*>(&lds[r * LDSW + wc * 64 + af * 16 + lg * 4]) = acc[bf][af];
            }
        }
        __syncthreads();
        #pragma unroll
        for (int p = 0; p < 4; ++p) {
            const int r = wv * 8 + p * 2 + half;   // 0..31
            const f32x4 v = *reinterpret_cast<const f32x4*>(&lds[r * LDSW + c4]);
            if (colok) {
                __builtin_nontemporal_store(
                    v, reinterpret_cast<f32x4*>(&outbase[(size_t)(ph * 32 + r) * CLASSES]));
            }
        }
    }
}

extern "C" void kernel_launch(void* const* d_in, const int* in_sizes, int n_in,
                              void* d_out, int out_size, void* d_ws, size_t ws_size,
                              hipStream_t stream) {
    const float* x = (const float*)d_in[0];   // (4096, 128)
    const float* w = (const float*)d_in[1];   // (128, 100000)
    float* out = (float*)d_out;               // (4096, 100000)

    unsigned short* xnt = (unsigned short*)d_ws;                  // 4096*128 bf16 = 1 MiB
    unsigned short* wnt = xnt + (size_t)BATCH * CHANNEL;          // 100096*128 bf16 = 25.6 MB
    const size_t need = ((size_t)BATCH * CHANNEL + (size_t)NPAD * CHANNEL) * sizeof(unsigned short);
    if (ws_size < need) return;

    xnorm_kernel<<<dim3(BATCH / 4), dim3(256), 0, stream>>>(x, xnt);
    wnorm_kernel<<<dim3((NPAD + 255) / 256), dim3(256), 0, stream>>>(w, wnt);
    cos_gemm_kernel<<<dim3(NWG), dim3(256), 0, stream>>>(xnt, wnt, out);
}

// Round 7
// 339.404 us; speedup vs baseline: 1.0421x; 1.0421x over previous
//
#include <hip/hip_runtime.h>
#include <hip/hip_bf16.h>
#include <stdint.h>

#define CLASSES 100000
#define CHANNEL 128
#define BATCH   4096
#define NPAD    100096   // 782 * 128 (class dim padded to 128-tile multiple)
#define NBM     64       // row tiles (4096/64)
#define NBN     782      // class tiles of 128
#define WNORM_BLOCKS ((NPAD + 255) / 256)   // 391
#define XNORM_BLOCKS (BATCH / 4)            // 1024

typedef __bf16 bf16x8 __attribute__((ext_vector_type(8)));
typedef float  f32x4  __attribute__((ext_vector_type(4)));
typedef unsigned short u16x8 __attribute__((ext_vector_type(8)));

__device__ __forceinline__ unsigned short f32_to_bf16_rne(float f) {
    union { float f; uint32_t u; } v; v.f = f;
    uint32_t u = v.u;
    return (unsigned short)((u + 0x7fffu + ((u >> 16) & 1u)) >> 16);
}

// ---------------------------------------------------------------------------
// MFMA-fragment-tiled operand layout (both xn and wn):
//   element (frag16 f, k) stored at  [((f*4 + ks)*64 + lane)*8 + j]
//   so every GEMM fragment load is one lane-contiguous 1 KB read.
// ---------------------------------------------------------------------------

__device__ __forceinline__ void xnorm_body(const float* __restrict__ x,
                                           unsigned short* __restrict__ xnt,
                                           int blk) {
    const int row  = blk * 4 + (threadIdx.x >> 6);
    const int lane = threadIdx.x & 63;
    const float2 v = *reinterpret_cast<const float2*>(&x[(size_t)row * CHANNEL + lane * 2]);
    float s = v.x * v.x + v.y * v.y;
    #pragma unroll
    for (int off = 32; off >= 1; off >>= 1) s += __shfl_xor(s, off);
    const float inv = rsqrtf(fmaxf(s, 1e-12f));
    const int rf  = row >> 4;
    const int l15 = row & 15;
    const int k0  = lane * 2;
    const int ks  = k0 >> 5;
    const int lg  = (k0 >> 3) & 3;
    const int j   = k0 & 7;
    ushort2 o;
    o.x = f32_to_bf16_rne(v.x * inv);
    o.y = f32_to_bf16_rne(v.y * inv);
    *reinterpret_cast<ushort2*>(
        &xnt[((size_t)(rf * 4 + ks) * 64 + lg * 16 + l15) * 8 + j]) = o;
}

__device__ __forceinline__ void wnorm_body(const float* __restrict__ w,
                                           unsigned short* __restrict__ wnt,
                                           int blk) {
    const int c = blk * 256 + threadIdx.x;
    if (c >= NPAD) return;
    const int cf  = c >> 4;
    const int l15 = c & 15;
    if (c >= CLASSES) {
        u16x8 z;
        #pragma unroll
        for (int i = 0; i < 8; ++i) z[i] = 0;
        #pragma unroll
        for (int ks = 0; ks < 4; ++ks)
            #pragma unroll
            for (int lg = 0; lg < 4; ++lg)
                *reinterpret_cast<u16x8*>(
                    &wnt[((size_t)(cf * 4 + ks) * 64 + lg * 16 + l15) * 8]) = z;
        return;
    }
    float s = 0.f;
    #pragma unroll 8
    for (int ch = 0; ch < CHANNEL; ++ch) {
        const float v = w[(size_t)ch * CLASSES + c];
        s += v * v;
    }
    const float inv = rsqrtf(fmaxf(s, 1e-12f));
    #pragma unroll
    for (int ks = 0; ks < 4; ++ks) {
        #pragma unroll
        for (int lg = 0; lg < 4; ++lg) {
            u16x8 o;
            #pragma unroll
            for (int j = 0; j < 8; ++j) {
                const float v = w[(size_t)(ks * 32 + lg * 8 + j) * CLASSES + c];
                o[j] = f32_to_bf16_rne(v * inv);
            }
            *reinterpret_cast<u16x8*>(
                &wnt[((size_t)(cf * 4 + ks) * 64 + lg * 16 + l15) * 8]) = o;
        }
    }
}

// Merged prep: blocks [0, WNORM_BLOCKS) normalize w columns; the rest do x rows.
__global__ void prep_kernel(const float* __restrict__ x, const float* __restrict__ w,
                            unsigned short* __restrict__ xnt, unsigned short* __restrict__ wnt) {
    const int b = blockIdx.x;
    if (b < WNORM_BLOCKS) wnorm_body(w, wnt, b);
    else                  xnorm_body(x, xnt, b - WNORM_BLOCKS);
}

// Block tile: 64 batch-rows x 128 classes; 4 waves (2x2), each 32 rows x 64 cols.
// R4 (best measured): two-phase LDS epilogue (16.9 KB) -> 8 blocks/CU, full
// occupancy; stores are 512 B-contiguous-per-row full-line writes.
// R6: swizzle reverted (R5 showed fetch locality is immaterial: ~100 MB of
// re-fetch is only ~16 us of BW; natural bm-fastest order writes adjacently).
#define LDSW 132
__global__ __launch_bounds__(256) void cos_gemm_kernel(const unsigned short* __restrict__ xnt,
                                                       const unsigned short* __restrict__ wnt,
                                                       float* __restrict__ out) {
    const int bm   = blockIdx.x;     // 0..63  (row tiles; fast dim)
    const int bn   = blockIdx.y;     // 0..781 (class tiles of 128)
    const int tid  = threadIdx.x;
    const int wv   = tid >> 6;
    const int wr   = wv >> 1;        // row half (0..1)
    const int wc   = wv & 1;         // col half (0..1)
    const int lane = tid & 63;
    const int l15  = lane & 15;
    const int lg   = lane >> 4;

    __shared__ float lds[32 * LDSW];

    f32x4 acc[2][4] = {};
    #pragma unroll
    for (int ks = 0; ks < 4; ++ks) {
        bf16x8 b[2], a[4];
        #pragma unroll
        for (int bf = 0; bf < 2; ++bf) {
            const int rf = bm * 4 + wr * 2 + bf;
            b[bf] = *reinterpret_cast<const bf16x8*>(
                &xnt[((size_t)(rf * 4 + ks) * 64 + lane) * 8]);
        }
        #pragma unroll
        for (int af = 0; af < 4; ++af) {
            const int cf = bn * 8 + wc * 4 + af;
            a[af] = *reinterpret_cast<const bf16x8*>(
                &wnt[((size_t)(cf * 4 + ks) * 64 + lane) * 8]);
        }
        #pragma unroll
        for (int bf = 0; bf < 2; ++bf)
            #pragma unroll
            for (int af = 0; af < 4; ++af)
                acc[bf][af] = __builtin_amdgcn_mfma_f32_16x16x32_bf16(a[af], b[bf], acc[bf][af], 0, 0, 0);
    }

    // Epilogue: phase ph stages rows [ph*32, ph*32+32) (held by waves wr==ph),
    // then all 4 waves stream them out, 2 rows x 512 B contiguous per store.
    const int  half = lane >> 5;          // 0..1
    const int  c4   = (lane & 31) * 4;    // 0..124
    const int  gcol = bn * 128 + c4;
    const bool colok = gcol < CLASSES;    // 100000 % 4 == 0: store fully in or out
    float* outbase = out + (size_t)(bm * 64) * CLASSES + gcol;

    #pragma unroll
    for (int ph = 0; ph < 2; ++ph) {
        if (ph) __syncthreads();          // drain phase-0 readers before overwrite
        if (wr == ph) {
            #pragma unroll
            for (int bf = 0; bf < 2; ++bf) {
                const int r = bf * 16 + l15;
                #pragma unroll
                for (int af = 0; af < 4; ++af)
                    *reinterpret_cast<f32x4*>(&lds[r * LDSW + wc * 64 + af * 16 + lg * 4]) = acc[bf][af];
            }
        }
        __syncthreads();
        #pragma unroll
        for (int p = 0; p < 4; ++p) {
            const int r = wv * 8 + p * 2 + half;   // 0..31
            const f32x4 v = *reinterpret_cast<const f32x4*>(&lds[r * LDSW + c4]);
            if (colok) {
                __builtin_nontemporal_store(
                    v, reinterpret_cast<f32x4*>(&outbase[(size_t)(ph * 32 + r) * CLASSES]));
            }
        }
    }
}

extern "C" void kernel_launch(void* const* d_in, const int* in_sizes, int n_in,
                              void* d_out, int out_size, void* d_ws, size_t ws_size,
                              hipStream_t stream) {
    const float* x = (const float*)d_in[0];   // (4096, 128)
    const float* w = (const float*)d_in[1];   // (128, 100000)
    float* out = (float*)d_out;               // (4096, 100000)

    unsigned short* xnt = (unsigned short*)d_ws;                  // 4096*128 bf16 = 1 MiB
    unsigned short* wnt = xnt + (size_t)BATCH * CHANNEL;          // 100096*128 bf16 = 25.6 MB
    const size_t need = ((size_t)BATCH * CHANNEL + (size_t)NPAD * CHANNEL) * sizeof(unsigned short);
    if (ws_size < need) return;

    prep_kernel<<<dim3(WNORM_BLOCKS + XNORM_BLOCKS), dim3(256), 0, stream>>>(x, w, xnt, wnt);
    cos_gemm_kernel<<<dim3(NBM, NBN), dim3(256), 0, stream>>>(xnt, wnt, out);
}